// Round 1
// baseline (588.647 us; speedup 1.0000x reference)
//
#include <hip/hip_runtime.h>
#include <cstdint>
#include <cstddef>

#define NEG_INF (-1.0e9f)

typedef __attribute__((ext_vector_type(8))) short bf16x8;
typedef __attribute__((ext_vector_type(8))) unsigned short u16x8;
typedef __attribute__((ext_vector_type(4))) float f32x4;

constexpr int BB = 64;     // batch
constexpr int NN = 2048;   // seq len
constexpr int HH = 512;    // h dim
constexpr int DD = 512;    // enc dim (GEMM K)
constexpr int AA = 512;    // attention dim (GEMM N)

constexpr int BM = 128;    // rows per workgroup
constexpr int BN = 128;    // a-cols per chunk
constexpr int BK = 32;     // K step
constexpr int LDT = 40;    // padded LDS row stride (ushorts); 80 B = 16-B aligned, conflict-free

__device__ __forceinline__ unsigned short f2bf(float x) {
  unsigned int u = __float_as_uint(x);
  return (unsigned short)((u + 0x8000u) >> 16);   // round-to-nearest on raw bits
}

__device__ __forceinline__ float fast_rcp(float x) {
#if __has_builtin(__builtin_amdgcn_rcpf)
  return __builtin_amdgcn_rcpf(x);
#else
  return 1.f / x;
#endif
}

__device__ __forceinline__ float fast_tanh(float x) {
  // tanh(x) = sign(x) * (1 - 2/(e^{2|x|}+1)); e=inf -> 1, x=0 -> 0
  float e = __expf(2.f * fabsf(x));
  float t = 1.f - 2.f * fast_rcp(e + 1.f);
  return copysignf(t, x);
}

__device__ __forceinline__ void cvt_store16(unsigned short* dst, const float4* s) {
  u16x8 p0, p1;
  p0[0]=f2bf(s[0].x); p0[1]=f2bf(s[0].y); p0[2]=f2bf(s[0].z); p0[3]=f2bf(s[0].w);
  p0[4]=f2bf(s[1].x); p0[5]=f2bf(s[1].y); p0[6]=f2bf(s[1].z); p0[7]=f2bf(s[1].w);
  p1[0]=f2bf(s[2].x); p1[1]=f2bf(s[2].y); p1[2]=f2bf(s[2].z); p1[3]=f2bf(s[2].w);
  p1[4]=f2bf(s[3].x); p1[5]=f2bf(s[3].y); p1[6]=f2bf(s[3].z); p1[7]=f2bf(s[3].w);
  *(u16x8*)dst = p0;
  *(u16x8*)(dst + 8) = p1;
}

// -------- proj_h: ph[b,a] = sum_h h[b,h] * Wh[a,h] --------
__global__ __launch_bounds__(256)
void proj_h_kernel(const float* __restrict__ h, const float* __restrict__ Wh,
                   float* __restrict__ ph) {
  __shared__ float hL[HH];
  const int b = blockIdx.x;
  for (int i = threadIdx.x; i < HH; i += 256) hL[i] = h[b * HH + i];
  __syncthreads();
  for (int a = threadIdx.x; a < AA; a += 256) {
    const float4* wr = (const float4*)(Wh + (size_t)a * HH);
    float acc = 0.f;
    #pragma unroll 4
    for (int j = 0; j < HH / 4; ++j) {
      float4 w = wr[j];
      acc += w.x * hL[4*j] + w.y * hL[4*j+1] + w.z * hL[4*j+2] + w.w * hL[4*j+3];
    }
    ph[b * AA + a] = acc;
  }
}

// -------- fused scores: scores[m] = sum_a v[a] * tanh(ph[b,a] + enc[m,:] . We[a,:]) --------
__global__ __launch_bounds__(256)
void scores_kernel(const float* __restrict__ enc, const float* __restrict__ We,
                   const float* __restrict__ ph, const float* __restrict__ vvec,
                   float* __restrict__ scores) {
  __shared__ unsigned short As[BM * LDT];
  __shared__ unsigned short Bs[BN * LDT];
  __shared__ float sRows[2][BM];
  __shared__ float phL[BN];
  __shared__ float vL[BN];

  const int tid  = threadIdx.x;
  const int m0   = blockIdx.x * BM;       // tile never crosses batch boundary (2048 % 128 == 0)
  const int b    = m0 >> 11;              // m0 / NN
  const int lane = tid & 63;
  const int wid  = tid >> 6;
  const int wm   = wid >> 1;              // wave row-half (0..1)
  const int wn   = wid & 1;               // wave col-half (0..1)
  const int c    = lane & 15;
  const int quad = lane >> 4;

  ((float*)sRows)[tid] = 0.f;

  // staging: thread covers row = tid>>1, 16 k-elems at seg = (tid&1)*16
  const int srow = tid >> 1;
  const int sseg = (tid & 1) << 4;
  const float* encRow = enc + (size_t)(m0 + srow) * DD + sseg;
  unsigned short* aDst = &As[srow * LDT + sseg];
  unsigned short* bDst = &Bs[srow * LDT + sseg];

  for (int ch = 0; ch < AA / BN; ++ch) {
    if (tid < BN) {
      phL[tid] = ph[b * AA + ch * BN + tid];
      vL[tid]  = vvec[ch * BN + tid];
    }
    f32x4 acc[4][4];
    #pragma unroll
    for (int i = 0; i < 4; ++i)
      #pragma unroll
      for (int j = 0; j < 4; ++j)
        acc[i][j] = (f32x4){0.f, 0.f, 0.f, 0.f};

    const float* weRow = We + (size_t)(ch * BN + srow) * DD + sseg;

    float4 av[4], bv[4];
    #pragma unroll
    for (int j = 0; j < 4; ++j) av[j] = *(const float4*)(encRow + 4 * j);
    #pragma unroll
    for (int j = 0; j < 4; ++j) bv[j] = *(const float4*)(weRow + 4 * j);

    for (int k0 = 0; k0 < DD; k0 += BK) {
      __syncthreads();                    // previous step's frag reads done
      cvt_store16(aDst, av);
      cvt_store16(bDst, bv);
      __syncthreads();                    // tiles staged
      if (k0 + BK < DD) {                 // prefetch next step (overlaps MFMA)
        #pragma unroll
        for (int j = 0; j < 4; ++j) av[j] = *(const float4*)(encRow + k0 + BK + 4 * j);
        #pragma unroll
        for (int j = 0; j < 4; ++j) bv[j] = *(const float4*)(weRow + k0 + BK + 4 * j);
      }
      bf16x8 af[4], bfv[4];
      #pragma unroll
      for (int t = 0; t < 4; ++t)
        af[t] = *(const bf16x8*)&As[(wm * 64 + t * 16 + c) * LDT + quad * 8];
      #pragma unroll
      for (int t = 0; t < 4; ++t)
        bfv[t] = *(const bf16x8*)&Bs[(wn * 64 + t * 16 + c) * LDT + quad * 8];
      #pragma unroll
      for (int i = 0; i < 4; ++i)
        #pragma unroll
        for (int j = 0; j < 4; ++j)
          acc[i][j] = __builtin_amdgcn_mfma_f32_16x16x32_bf16(af[i], bfv[j], acc[i][j], 0, 0, 0);
    }

    // epilogue: energy = tanh(acc + ph), partial score = sum_a v*energy
    // C/D layout: row = quad*4 + r, col = c (m89-verified)
    float pp[4], vv[4];
    #pragma unroll
    for (int t = 0; t < 4; ++t) {
      int col = wn * 64 + t * 16 + c;
      pp[t] = phL[col];
      vv[t] = vL[col];
    }
    #pragma unroll
    for (int i = 0; i < 4; ++i) {
      #pragma unroll
      for (int r = 0; r < 4; ++r) {
        float p = 0.f;
        #pragma unroll
        for (int j = 0; j < 4; ++j) {
          float x = acc[i][j][r] + pp[j];
          p += vv[j] * fast_tanh(x);
        }
        // reduce across the 16 cols held by this quad (lane bits 0..3)
        p += __shfl_xor(p, 1, 64);
        p += __shfl_xor(p, 2, 64);
        p += __shfl_xor(p, 4, 64);
        p += __shfl_xor(p, 8, 64);
        if (c == 0) sRows[wn][wm * 64 + i * 16 + quad * 4 + r] += p;
      }
    }
    __syncthreads();   // protect phL/vL rewrite + sRows for final read
  }

  if (tid < BM) scores[m0 + tid] = sRows[0][tid] + sRows[1][tid];
}

// -------- masked softmax over N per batch; writes alpha to d_out --------
__global__ __launch_bounds__(256)
void softmax_kernel(const float* __restrict__ scores, const int* __restrict__ mask,
                    float* __restrict__ alpha) {
  const int b = blockIdx.x, tid = threadIdx.x;
  const int base = b * NN;
  float vals[8];
  float mx = -3.4e38f;
  #pragma unroll
  for (int i = 0; i < 8; ++i) {
    int n = tid + 256 * i;
    float s = scores[base + n];
    if (mask[base + n] == 0) s = NEG_INF;
    vals[i] = s;
    mx = fmaxf(mx, s);
  }
  #pragma unroll
  for (int o = 32; o; o >>= 1) mx = fmaxf(mx, __shfl_xor(mx, o, 64));
  __shared__ float w4[4];
  if ((tid & 63) == 0) w4[tid >> 6] = mx;
  __syncthreads();
  mx = fmaxf(fmaxf(w4[0], w4[1]), fmaxf(w4[2], w4[3]));
  float sum = 0.f;
  #pragma unroll
  for (int i = 0; i < 8; ++i) { vals[i] = __expf(vals[i] - mx); sum += vals[i]; }
  #pragma unroll
  for (int o = 32; o; o >>= 1) sum += __shfl_xor(sum, o, 64);
  __shared__ float s4[4];
  if ((tid & 63) == 0) s4[tid >> 6] = sum;
  __syncthreads();
  sum = s4[0] + s4[1] + s4[2] + s4[3];
  float inv = 1.f / sum;
  #pragma unroll
  for (int i = 0; i < 8; ++i) alpha[base + tid + 256 * i] = vals[i] * inv;
}

// -------- context[b,d] = sum_n alpha[b,n] * enc[b,n,d]  (fp32, atomic partials) --------
__global__ __launch_bounds__(128)
void context_kernel(const float* __restrict__ enc, const float* __restrict__ alpha,
                    float* __restrict__ ctx) {
  const int b  = blockIdx.x;
  const int nc = blockIdx.y;     // 8 chunks of 256 n each
  const int t  = threadIdx.x;    // 128 threads, float4 over D=512
  __shared__ float aL[256];
  aL[t]       = alpha[b * NN + nc * 256 + t];
  aL[t + 128] = alpha[b * NN + nc * 256 + t + 128];
  __syncthreads();
  const float* ep = enc + ((size_t)b * NN + nc * 256) * DD + t * 4;
  float4 acc = {0.f, 0.f, 0.f, 0.f};
  for (int n = 0; n < 256; ++n) {
    float4 e = *(const float4*)(ep + (size_t)n * DD);
    float a = aL[n];
    acc.x += a * e.x; acc.y += a * e.y; acc.z += a * e.z; acc.w += a * e.w;
  }
  float* o = ctx + b * DD + t * 4;
  atomicAdd(o + 0, acc.x);
  atomicAdd(o + 1, acc.y);
  atomicAdd(o + 2, acc.z);
  atomicAdd(o + 3, acc.w);
}

extern "C" void kernel_launch(void* const* d_in, const int* in_sizes, int n_in,
                              void* d_out, int out_size, void* d_ws, size_t ws_size,
                              hipStream_t stream) {
  const float* h    = (const float*)d_in[0];
  const float* enc  = (const float*)d_in[1];
  const int*   mask = (const int*)d_in[2];
  const float* Wh   = (const float*)d_in[3];
  const float* We   = (const float*)d_in[4];
  const float* v    = (const float*)d_in[5];

  float* out   = (float*)d_out;
  float* ctx   = out;                 // (B, D) = 64*512
  float* alpha = out + BB * DD;       // (B, N) = 64*2048

  float* ph     = (float*)d_ws;       // (B, A)
  float* scores = ph + BB * AA;       // (B, N)

  hipMemsetAsync(ctx, 0, (size_t)BB * DD * sizeof(float), stream);
  proj_h_kernel<<<BB, 256, 0, stream>>>(h, Wh, ph);
  scores_kernel<<<(BB * NN) / BM, 256, 0, stream>>>(enc, We, ph, v, scores);
  softmax_kernel<<<BB, 256, 0, stream>>>(scores, mask, alpha);
  context_kernel<<<dim3(BB, 8), 128, 0, stream>>>(enc, alpha, ctx);
}

// Round 2
// 567.069 us; speedup vs baseline: 1.0381x; 1.0381x over previous
//
#include <hip/hip_runtime.h>
#include <cstdint>
#include <cstddef>

#define NEG_INF (-1.0e9f)

typedef __attribute__((ext_vector_type(8))) short bf16x8;
typedef __attribute__((ext_vector_type(8))) unsigned short u16x8;
typedef __attribute__((ext_vector_type(4))) float f32x4;

constexpr int BB = 64;     // batch
constexpr int NN = 2048;   // seq len
constexpr int HH = 512;    // h dim
constexpr int DD = 512;    // enc dim (GEMM K)
constexpr int AA = 512;    // attention dim (GEMM N)

constexpr int BM = 128;    // rows per workgroup
constexpr int BN = 128;    // a-cols per chunk
constexpr int BK = 32;     // K step
constexpr int LDT = 40;    // padded stride for the fallback (VALU-staged) kernel only

__device__ __forceinline__ unsigned short f2bf(float x) {
  unsigned int u = __float_as_uint(x);
  return (unsigned short)((u + 0x8000u) >> 16);   // round-to-nearest on raw bits
}

__device__ __forceinline__ float fast_rcp(float x) {
#if __has_builtin(__builtin_amdgcn_rcpf)
  return __builtin_amdgcn_rcpf(x);
#else
  return 1.f / x;
#endif
}

__device__ __forceinline__ float fast_tanh(float x) {
  float e = __expf(2.f * fabsf(x));
  float t = 1.f - 2.f * fast_rcp(e + 1.f);
  return copysignf(t, x);
}

// async global->LDS, 16 B per lane; LDS dest = wave-uniform base + lane*16 (m97/m104)
__device__ __forceinline__ void gload16(const void* g, void* l) {
  __builtin_amdgcn_global_load_lds(
      (const __attribute__((address_space(1))) unsigned int*)g,
      (__attribute__((address_space(3))) unsigned int*)l, 16, 0, 0);
}

__device__ __forceinline__ void cvt_pack(const float4* s, u16x8& p0, u16x8& p1) {
  p0[0]=f2bf(s[0].x); p0[1]=f2bf(s[0].y); p0[2]=f2bf(s[0].z); p0[3]=f2bf(s[0].w);
  p0[4]=f2bf(s[1].x); p0[5]=f2bf(s[1].y); p0[6]=f2bf(s[1].z); p0[7]=f2bf(s[1].w);
  p1[0]=f2bf(s[2].x); p1[1]=f2bf(s[2].y); p1[2]=f2bf(s[2].z); p1[3]=f2bf(s[2].w);
  p1[4]=f2bf(s[3].x); p1[5]=f2bf(s[3].y); p1[6]=f2bf(s[3].z); p1[7]=f2bf(s[3].w);
}

// -------- We -> bf16 cast (512 KB ws) --------
__global__ __launch_bounds__(256)
void we_cast_kernel(const float* __restrict__ We, unsigned short* __restrict__ web) {
  int i = (blockIdx.x * 256 + threadIdx.x) * 8;   // 262144 elems / 8 = 32768 threads
  if (i >= AA * DD) return;
  float4 s[2];
  s[0] = *(const float4*)(We + i);
  s[1] = *(const float4*)(We + i + 4);
  u16x8 p;
  p[0]=f2bf(s[0].x); p[1]=f2bf(s[0].y); p[2]=f2bf(s[0].z); p[3]=f2bf(s[0].w);
  p[4]=f2bf(s[1].x); p[5]=f2bf(s[1].y); p[6]=f2bf(s[1].z); p[7]=f2bf(s[1].w);
  *(u16x8*)(web + i) = p;
}

// -------- proj_h: ph[b,a] = sum_h h[b,h] * Wh[a,h] --------
__global__ __launch_bounds__(256)
void proj_h_kernel(const float* __restrict__ h, const float* __restrict__ Wh,
                   float* __restrict__ ph) {
  __shared__ float hL[HH];
  const int b = blockIdx.x;
  hL[threadIdx.x]       = h[b * HH + threadIdx.x];
  hL[threadIdx.x + 256] = h[b * HH + threadIdx.x + 256];
  __syncthreads();
  const int a = blockIdx.y * 256 + threadIdx.x;
  const float4* wr = (const float4*)(Wh + (size_t)a * HH);
  float acc = 0.f;
  #pragma unroll 4
  for (int j = 0; j < HH / 4; ++j) {
    float4 w = wr[j];
    acc += w.x * hL[4*j] + w.y * hL[4*j+1] + w.z * hL[4*j+2] + w.w * hL[4*j+3];
  }
  ph[b * AA + a] = acc;
}

// -------- fused scores, m97-structure (global_load_lds) --------
// chunk 0: A staged fp32->bf16 via VALU AND written to encb ws; chunks 1-3: A via global_load_lds.
// B always via global_load_lds from web (bf16 ws).
__global__ __launch_bounds__(256)
void scores_fused(const float* __restrict__ enc, const unsigned short* __restrict__ web,
                  const float* __restrict__ ph, const float* __restrict__ vvec,
                  unsigned short* __restrict__ encb, float* __restrict__ scores) {
  __shared__ unsigned short As[BM * BK];   // unpadded [128][32] (global_load_lds constraint)
  __shared__ unsigned short Bs[BN * BK];
  __shared__ float sRows[2][BM];
  __shared__ float phL[BN];
  __shared__ float vL[BN];

  const int tid  = threadIdx.x;
  const int m0   = blockIdx.x * BM;
  const int b    = m0 >> 11;
  const int lane = tid & 63;
  const int wid  = tid >> 6;
  const int wm   = wid >> 1;
  const int wn   = wid & 1;
  const int c    = lane & 15;
  const int quad = lane >> 4;

  ((float*)sRows)[tid] = 0.f;

  // fast-path staging coords: wave wid, instr t covers rows wid*32+t*16 .. +15
  const int gr = lane >> 2;          // row within 16-row group
  const int gk = (lane & 3) * 8;     // ushort offset of this lane's 16-B segment

  // slow-path (chunk 0) A staging coords
  const int srow = tid >> 1;
  const int sseg = (tid & 1) << 4;
  const float* encRow = enc + (size_t)(m0 + srow) * DD + sseg;
  unsigned short* wsRow = encb + (size_t)(m0 + srow) * DD + sseg;
  unsigned short* aDst = &As[srow * BK + sseg];

  for (int ch = 0; ch < AA / BN; ++ch) {
    if (tid < BN) {
      phL[tid] = ph[b * AA + ch * BN + tid];
      vL[tid]  = vvec[ch * BN + tid];
    }
    f32x4 acc[4][4];
    #pragma unroll
    for (int i = 0; i < 4; ++i)
      #pragma unroll
      for (int j = 0; j < 4; ++j)
        acc[i][j] = (f32x4){0.f, 0.f, 0.f, 0.f};

    if (ch == 0) {
      // ---- slow path: A from fp32 (VALU cast + ws writeback), B via gload ----
      float4 av[4];
      #pragma unroll
      for (int j = 0; j < 4; ++j) av[j] = *(const float4*)(encRow + 4 * j);

      for (int k0 = 0; k0 < DD; k0 += BK) {
        __syncthreads();                    // previous step's frag reads done
        #pragma unroll
        for (int t = 0; t < 2; ++t) {
          const int brow = wid * 32 + t * 16 + gr;
          gload16(web + (size_t)brow * DD + k0 + gk, &Bs[(wid * 32 + t * 16) * BK]);
        }
        u16x8 p0, p1;
        cvt_pack(av, p0, p1);
        *(u16x8*)aDst = p0;
        *(u16x8*)(aDst + 8) = p1;
        *(u16x8*)(wsRow + k0) = p0;         // bf16 writeback for chunks 1-3
        *(u16x8*)(wsRow + k0 + 8) = p1;
        __syncthreads();                    // drains lgkm (ds_write) + vmcnt (gload)
        if (k0 + BK < DD) {
          #pragma unroll
          for (int j = 0; j < 4; ++j) av[j] = *(const float4*)(encRow + k0 + BK + 4 * j);
        }
        bf16x8 af[4], bfv[4];
        #pragma unroll
        for (int t = 0; t < 4; ++t)
          af[t] = *(const bf16x8*)&As[(wm * 64 + t * 16 + c) * BK + quad * 8];
        #pragma unroll
        for (int t = 0; t < 4; ++t)
          bfv[t] = *(const bf16x8*)&Bs[(wn * 64 + t * 16 + c) * BK + quad * 8];
        #pragma unroll
        for (int i = 0; i < 4; ++i)
          #pragma unroll
          for (int j = 0; j < 4; ++j)
            acc[i][j] = __builtin_amdgcn_mfma_f32_16x16x32_bf16(af[i], bfv[j], acc[i][j], 0, 0, 0);
      }
    } else {
      // ---- fast path: both tiles via global_load_lds dwordx4 ----
      for (int k0 = 0; k0 < DD; k0 += BK) {
        __syncthreads();
        #pragma unroll
        for (int t = 0; t < 2; ++t) {
          const int row = wid * 32 + t * 16 + gr;
          gload16(encb + (size_t)(m0 + row) * DD + k0 + gk, &As[(wid * 32 + t * 16) * BK]);
          gload16(web + (size_t)(ch * BN + row) * DD + k0 + gk, &Bs[(wid * 32 + t * 16) * BK]);
        }
        __syncthreads();                    // vmcnt(0) drain before frag reads
        bf16x8 af[4], bfv[4];
        #pragma unroll
        for (int t = 0; t < 4; ++t)
          af[t] = *(const bf16x8*)&As[(wm * 64 + t * 16 + c) * BK + quad * 8];
        #pragma unroll
        for (int t = 0; t < 4; ++t)
          bfv[t] = *(const bf16x8*)&Bs[(wn * 64 + t * 16 + c) * BK + quad * 8];
        #pragma unroll
        for (int i = 0; i < 4; ++i)
          #pragma unroll
          for (int j = 0; j < 4; ++j)
            acc[i][j] = __builtin_amdgcn_mfma_f32_16x16x32_bf16(af[i], bfv[j], acc[i][j], 0, 0, 0);
      }
    }

    // epilogue: partial score += sum_a v[a]*tanh(acc + ph[a]); C/D row = quad*4+r, col = c
    float pp[4], vv[4];
    #pragma unroll
    for (int t = 0; t < 4; ++t) {
      int col = wn * 64 + t * 16 + c;
      pp[t] = phL[col];
      vv[t] = vL[col];
    }
    #pragma unroll
    for (int i = 0; i < 4; ++i) {
      #pragma unroll
      for (int r = 0; r < 4; ++r) {
        float p = 0.f;
        #pragma unroll
        for (int j = 0; j < 4; ++j) {
          float x = acc[i][j][r] + pp[j];
          p += vv[j] * fast_tanh(x);
        }
        p += __shfl_xor(p, 1, 64);
        p += __shfl_xor(p, 2, 64);
        p += __shfl_xor(p, 4, 64);
        p += __shfl_xor(p, 8, 64);
        if (c == 0) sRows[wn][wm * 64 + i * 16 + quad * 4 + r] += p;
      }
    }
    __syncthreads();   // protect phL/vL rewrite + sRows
  }

  if (tid < BM) scores[m0 + tid] = sRows[0][tid] + sRows[1][tid];
}

// -------- fallback scores (round-1, fp32 inputs, VALU staging; no ws enc) --------
__global__ __launch_bounds__(256)
void scores_kernel_fb(const float* __restrict__ enc, const float* __restrict__ We,
                      const float* __restrict__ ph, const float* __restrict__ vvec,
                      float* __restrict__ scores) {
  __shared__ unsigned short As[BM * LDT];
  __shared__ unsigned short Bs[BN * LDT];
  __shared__ float sRows[2][BM];
  __shared__ float phL[BN];
  __shared__ float vL[BN];

  const int tid  = threadIdx.x;
  const int m0   = blockIdx.x * BM;
  const int b    = m0 >> 11;
  const int lane = tid & 63;
  const int wid  = tid >> 6;
  const int wm   = wid >> 1;
  const int wn   = wid & 1;
  const int c    = lane & 15;
  const int quad = lane >> 4;

  ((float*)sRows)[tid] = 0.f;

  const int srow = tid >> 1;
  const int sseg = (tid & 1) << 4;
  const float* encRow = enc + (size_t)(m0 + srow) * DD + sseg;
  unsigned short* aDst = &As[srow * LDT + sseg];
  unsigned short* bDst = &Bs[srow * LDT + sseg];

  for (int ch = 0; ch < AA / BN; ++ch) {
    if (tid < BN) {
      phL[tid] = ph[b * AA + ch * BN + tid];
      vL[tid]  = vvec[ch * BN + tid];
    }
    f32x4 acc[4][4];
    #pragma unroll
    for (int i = 0; i < 4; ++i)
      #pragma unroll
      for (int j = 0; j < 4; ++j)
        acc[i][j] = (f32x4){0.f, 0.f, 0.f, 0.f};

    const float* weRow = We + (size_t)(ch * BN + srow) * DD + sseg;
    float4 av[4], bv[4];
    #pragma unroll
    for (int j = 0; j < 4; ++j) av[j] = *(const float4*)(encRow + 4 * j);
    #pragma unroll
    for (int j = 0; j < 4; ++j) bv[j] = *(const float4*)(weRow + 4 * j);

    for (int k0 = 0; k0 < DD; k0 += BK) {
      __syncthreads();
      u16x8 a0, a1, b0, b1;
      cvt_pack(av, a0, a1);
      cvt_pack(bv, b0, b1);
      *(u16x8*)aDst = a0; *(u16x8*)(aDst + 8) = a1;
      *(u16x8*)bDst = b0; *(u16x8*)(bDst + 8) = b1;
      __syncthreads();
      if (k0 + BK < DD) {
        #pragma unroll
        for (int j = 0; j < 4; ++j) av[j] = *(const float4*)(encRow + k0 + BK + 4 * j);
        #pragma unroll
        for (int j = 0; j < 4; ++j) bv[j] = *(const float4*)(weRow + k0 + BK + 4 * j);
      }
      bf16x8 af[4], bfv[4];
      #pragma unroll
      for (int t = 0; t < 4; ++t)
        af[t] = *(const bf16x8*)&As[(wm * 64 + t * 16 + c) * LDT + quad * 8];
      #pragma unroll
      for (int t = 0; t < 4; ++t)
        bfv[t] = *(const bf16x8*)&Bs[(wn * 64 + t * 16 + c) * LDT + quad * 8];
      #pragma unroll
      for (int i = 0; i < 4; ++i)
        #pragma unroll
        for (int j = 0; j < 4; ++j)
          acc[i][j] = __builtin_amdgcn_mfma_f32_16x16x32_bf16(af[i], bfv[j], acc[i][j], 0, 0, 0);
    }

    float pp[4], vv[4];
    #pragma unroll
    for (int t = 0; t < 4; ++t) {
      int col = wn * 64 + t * 16 + c;
      pp[t] = phL[col];
      vv[t] = vL[col];
    }
    #pragma unroll
    for (int i = 0; i < 4; ++i) {
      #pragma unroll
      for (int r = 0; r < 4; ++r) {
        float p = 0.f;
        #pragma unroll
        for (int j = 0; j < 4; ++j) {
          float x = acc[i][j][r] + pp[j];
          p += vv[j] * fast_tanh(x);
        }
        p += __shfl_xor(p, 1, 64);
        p += __shfl_xor(p, 2, 64);
        p += __shfl_xor(p, 4, 64);
        p += __shfl_xor(p, 8, 64);
        if (c == 0) sRows[wn][wm * 64 + i * 16 + quad * 4 + r] += p;
      }
    }
    __syncthreads();
  }

  if (tid < BM) scores[m0 + tid] = sRows[0][tid] + sRows[1][tid];
}

// -------- masked softmax over N per batch; writes alpha to d_out --------
__global__ __launch_bounds__(256)
void softmax_kernel(const float* __restrict__ scores, const int* __restrict__ mask,
                    float* __restrict__ alpha) {
  const int b = blockIdx.x, tid = threadIdx.x;
  const int base = b * NN;
  float vals[8];
  float mx = -3.4e38f;
  #pragma unroll
  for (int i = 0; i < 8; ++i) {
    int n = tid + 256 * i;
    float s = scores[base + n];
    if (mask[base + n] == 0) s = NEG_INF;
    vals[i] = s;
    mx = fmaxf(mx, s);
  }
  #pragma unroll
  for (int o = 32; o; o >>= 1) mx = fmaxf(mx, __shfl_xor(mx, o, 64));
  __shared__ float w4[4];
  if ((tid & 63) == 0) w4[tid >> 6] = mx;
  __syncthreads();
  mx = fmaxf(fmaxf(w4[0], w4[1]), fmaxf(w4[2], w4[3]));
  float sum = 0.f;
  #pragma unroll
  for (int i = 0; i < 8; ++i) { vals[i] = __expf(vals[i] - mx); sum += vals[i]; }
  #pragma unroll
  for (int o = 32; o; o >>= 1) sum += __shfl_xor(sum, o, 64);
  __shared__ float s4[4];
  if ((tid & 63) == 0) s4[tid >> 6] = sum;
  __syncthreads();
  sum = s4[0] + s4[1] + s4[2] + s4[3];
  float inv = 1.f / sum;
  #pragma unroll
  for (int i = 0; i < 8; ++i) alpha[base + tid + 256 * i] = vals[i] * inv;
}

// -------- context partials: cpart[b,nc,d] = sum_{n in chunk} alpha*enc (no atomics) --------
__global__ __launch_bounds__(128)
void context_part(const float* __restrict__ enc, const float* __restrict__ alpha,
                  float* __restrict__ cpart) {
  const int b  = blockIdx.x;
  const int nc = blockIdx.y;     // 16 chunks of 128 n
  const int t  = threadIdx.x;    // 128 threads, float4 over D=512
  __shared__ float aL[128];
  aL[t] = alpha[b * NN + nc * 128 + t];
  __syncthreads();
  const float* ep = enc + ((size_t)b * NN + nc * 128) * DD + t * 4;
  float4 acc = {0.f, 0.f, 0.f, 0.f};
  for (int n = 0; n < 128; ++n) {
    float4 e = *(const float4*)(ep + (size_t)n * DD);
    float a = aL[n];
    acc.x += a * e.x; acc.y += a * e.y; acc.z += a * e.z; acc.w += a * e.w;
  }
  *(float4*)(cpart + ((size_t)(b * 16 + nc)) * DD + t * 4) = acc;
}

__global__ __launch_bounds__(256)
void context_reduce(const float* __restrict__ cpart, float* __restrict__ ctx) {
  const int i = blockIdx.x * 256 + threadIdx.x;   // 32768 = 64*512
  const int b = i >> 9, d = i & 511;
  float s = 0.f;
  #pragma unroll
  for (int nc = 0; nc < 16; ++nc) s += cpart[((size_t)(b * 16 + nc)) * DD + d];
  ctx[i] = s;
}

// -------- atomic-context fallback --------
__global__ __launch_bounds__(128)
void context_atomic(const float* __restrict__ enc, const float* __restrict__ alpha,
                    float* __restrict__ ctx) {
  const int b  = blockIdx.x;
  const int nc = blockIdx.y;
  const int t  = threadIdx.x;
  __shared__ float aL[256];
  aL[t]       = alpha[b * NN + nc * 256 + t];
  aL[t + 128] = alpha[b * NN + nc * 256 + t + 128];
  __syncthreads();
  const float* ep = enc + ((size_t)b * NN + nc * 256) * DD + t * 4;
  float4 acc = {0.f, 0.f, 0.f, 0.f};
  for (int n = 0; n < 256; ++n) {
    float4 e = *(const float4*)(ep + (size_t)n * DD);
    float a = aL[n];
    acc.x += a * e.x; acc.y += a * e.y; acc.z += a * e.z; acc.w += a * e.w;
  }
  float* o = ctx + b * DD + t * 4;
  atomicAdd(o + 0, acc.x);
  atomicAdd(o + 1, acc.y);
  atomicAdd(o + 2, acc.z);
  atomicAdd(o + 3, acc.w);
}

extern "C" void kernel_launch(void* const* d_in, const int* in_sizes, int n_in,
                              void* d_out, int out_size, void* d_ws, size_t ws_size,
                              hipStream_t stream) {
  const float* h    = (const float*)d_in[0];
  const float* enc  = (const float*)d_in[1];
  const int*   mask = (const int*)d_in[2];
  const float* Wh   = (const float*)d_in[3];
  const float* We   = (const float*)d_in[4];
  const float* v    = (const float*)d_in[5];

  float* out   = (float*)d_out;
  float* ctx   = out;                 // (B, D)
  float* alpha = out + BB * DD;       // (B, N)

  const size_t encb_bytes = (size_t)BB * NN * DD * sizeof(unsigned short); // 134 MB
  const size_t web_bytes  = (size_t)AA * DD * sizeof(unsigned short);      // 512 KB
  const size_t ph_bytes   = (size_t)BB * AA * sizeof(float);
  const size_t sc_bytes   = (size_t)BB * NN * sizeof(float);
  const size_t cp_bytes   = (size_t)BB * 16 * DD * sizeof(float);          // 2 MB
  const size_t need_full  = encb_bytes + web_bytes + ph_bytes + sc_bytes + cp_bytes;
  const size_t need_fb    = ph_bytes + sc_bytes;

  char* w = (char*)d_ws;

  if (ws_size >= need_full) {
    unsigned short* encb = (unsigned short*)w;
    unsigned short* web  = (unsigned short*)(w + encb_bytes);
    float* ph     = (float*)(w + encb_bytes + web_bytes);
    float* scores = ph + BB * AA;
    float* cpart  = scores + BB * NN;

    we_cast_kernel<<<(AA * DD / 8 + 255) / 256, 256, 0, stream>>>(We, web);
    proj_h_kernel<<<dim3(BB, 2), 256, 0, stream>>>(h, Wh, ph);
    scores_fused<<<(BB * NN) / BM, 256, 0, stream>>>(enc, web, ph, v, encb, scores);
    softmax_kernel<<<BB, 256, 0, stream>>>(scores, mask, alpha);
    context_part<<<dim3(BB, 16), 128, 0, stream>>>(enc, alpha, cpart);
    context_reduce<<<(BB * DD) / 256, 256, 0, stream>>>(cpart, ctx);
  } else {
    float* ph     = (float*)w;
    float* scores = ph + BB * AA;
    hipMemsetAsync(ctx, 0, (size_t)BB * DD * sizeof(float), stream);
    proj_h_kernel<<<dim3(BB, 2), 256, 0, stream>>>(h, Wh, ph);
    scores_kernel_fb<<<(BB * NN) / BM, 256, 0, stream>>>(enc, We, ph, v, scores);
    softmax_kernel<<<BB, 256, 0, stream>>>(scores, mask, alpha);
    context_atomic<<<dim3(BB, 8), 128, 0, stream>>>(enc, alpha, ctx);
  }
  (void)need_fb; (void)in_sizes; (void)n_in; (void)out_size;
}